// Round 1
// baseline (905.742 us; speedup 1.0000x reference)
//
#include <hip/hip_runtime.h>
#include <math.h>

// ---------------- problem constants (match reference) ----------------
// N=50000, F_IN=128, HID=64, HEADS1=4 (C1=256), NUM_GRAPHS=64, slope=0.2

// ---------------- small utility kernels ----------------
__global__ void k_zero_i32(int* __restrict__ p, int n) {
  int i = blockIdx.x * blockDim.x + threadIdx.x;
  if (i < n) p[i] = 0;
}

// degree histogram over dst (real edges + implicit self loops)
__global__ void k_hist(const int* __restrict__ edst, int E, int N, int* __restrict__ deg) {
  int stride = gridDim.x * blockDim.x;
  int EE = E + N;
  for (int i = blockIdx.x * blockDim.x + threadIdx.x; i < EE; i += stride) {
    int d = (i < E) ? edst[i] : (i - E);
    atomicAdd(&deg[d], 1);
  }
}

__global__ void k_ghist(const int* __restrict__ batch, int N, int* __restrict__ gcnt) {
  int stride = gridDim.x * blockDim.x;
  for (int i = blockIdx.x * blockDim.x + threadIdx.x; i < N; i += stride)
    atomicAdd(&gcnt[batch[i]], 1);
}

// single-block exclusive scan over n entries (n ~ 50000) -> offsets[0..n], cursor copy
__global__ void k_scan(const int* __restrict__ deg, int n,
                       int* __restrict__ offsets, int* __restrict__ cursor) {
  __shared__ int buf[1024];
  __shared__ int carry_s;
  if (threadIdx.x == 0) carry_s = 0;
  __syncthreads();
  for (int base = 0; base < n; base += 1024) {
    int i = base + threadIdx.x;
    int v = (i < n) ? deg[i] : 0;
    buf[threadIdx.x] = v;
    __syncthreads();
    for (int off = 1; off < 1024; off <<= 1) {
      int t = (threadIdx.x >= off) ? buf[threadIdx.x - off] : 0;
      __syncthreads();
      buf[threadIdx.x] += t;
      __syncthreads();
    }
    int excl = buf[threadIdx.x] - v;
    int c = carry_s;
    if (i < n) { int o = c + excl; offsets[i] = o; cursor[i] = o; }
    __syncthreads();
    if (threadIdx.x == 1023) carry_s = c + buf[1023];
    __syncthreads();
  }
  if (threadIdx.x == 0) offsets[n] = carry_s;
}

// tiny serial scan for 64 graphs
__global__ void k_gscan(const int* __restrict__ gcnt, int* __restrict__ gstart) {
  if (threadIdx.x == 0) {
    int acc = 0;
    for (int g = 0; g < 64; ++g) { gstart[g] = acc; acc += gcnt[g]; }
  }
}

// scatter edges into dst-sorted order (src ids only; self loops appended)
__global__ void k_scatter(const int* __restrict__ esrc, const int* __restrict__ edst,
                          int E, int N, int* __restrict__ cursor, int* __restrict__ ssrc) {
  int stride = gridDim.x * blockDim.x;
  int EE = E + N;
  for (int i = blockIdx.x * blockDim.x + threadIdx.x; i < EE; i += stride) {
    int d, s;
    if (i < E) { d = edst[i]; s = esrc[i]; }
    else       { d = i - E;   s = i - E;   }
    int pos = atomicAdd(&cursor[d], 1);
    ssrc[pos] = s;
  }
}

// ---------------- f32 tiled GEMM: C[M,Nn] = A[M,K] @ B[K,Nn] ----------------
// 64x64 tile, 256 threads, 4x4 micro-tile, K-step 32. K%32==0, Nn%64==0 assumed.
__global__ void k_gemm(const float* __restrict__ A, const float* __restrict__ B,
                       float* __restrict__ C, int M, int Nn, int K) {
  __shared__ float As[32][65];   // [kk][row], padded to kill write conflicts
  __shared__ float Bs[32][64];   // [kk][col]
  int tx = threadIdx.x & 15, ty = threadIdx.x >> 4;
  int row0 = blockIdx.x * 64, col0 = blockIdx.y * 64;
  float acc[4][4] = {};
  for (int k0 = 0; k0 < K; k0 += 32) {
    #pragma unroll
    for (int idx = threadIdx.x; idx < 64 * 32; idx += 256) {
      int r = idx >> 5, kk = idx & 31;
      int gr = row0 + r;
      As[kk][r] = (gr < M) ? A[(size_t)gr * K + k0 + kk] : 0.f;
    }
    #pragma unroll
    for (int idx = threadIdx.x; idx < 32 * 64; idx += 256) {
      int kk = idx >> 6, cc = idx & 63;
      Bs[kk][cc] = B[(size_t)(k0 + kk) * Nn + col0 + cc];
    }
    __syncthreads();
    #pragma unroll
    for (int kk = 0; kk < 32; ++kk) {
      float a[4], b[4];
      #pragma unroll
      for (int i = 0; i < 4; i++) a[i] = As[kk][ty * 4 + i];
      #pragma unroll
      for (int j = 0; j < 4; j++) b[j] = Bs[kk][tx * 4 + j];
      #pragma unroll
      for (int i = 0; i < 4; i++)
        #pragma unroll
        for (int j = 0; j < 4; j++)
          acc[i][j] += a[i] * b[j];
    }
    __syncthreads();
  }
  #pragma unroll
  for (int i = 0; i < 4; i++) {
    int gr = row0 + ty * 4 + i;
    if (gr < M) {
      float4 v = make_float4(acc[i][0], acc[i][1], acc[i][2], acc[i][3]);
      *(float4*)(C + (size_t)gr * Nn + col0 + tx * 4) = v;
    }
  }
}

// ---------------- attention logits, layer 1 (4 heads x 64 ch) ----------------
// one wave per node; lane covers 4 channels of one head
__global__ void k_logits1(const float* __restrict__ h1, const float* __restrict__ a_src,
                          const float* __restrict__ a_dst, float* __restrict__ as1,
                          float* __restrict__ ad1, int N) {
  int gt = blockIdx.x * blockDim.x + threadIdx.x;
  int wid = gt >> 6, lane = gt & 63;
  if (wid >= N) return;
  int head = lane >> 4, coff = (lane & 15) << 2;
  float4 hv = *(const float4*)(h1 + (size_t)wid * 256 + head * 64 + coff);
  float4 sv = *(const float4*)(a_src + head * 64 + coff);
  float4 dv = *(const float4*)(a_dst + head * 64 + coff);
  float ps = hv.x * sv.x + hv.y * sv.y + hv.z * sv.z + hv.w * sv.w;
  float pd = hv.x * dv.x + hv.y * dv.y + hv.z * dv.z + hv.w * dv.w;
  #pragma unroll
  for (int off = 1; off < 16; off <<= 1) {
    ps += __shfl_xor(ps, off);
    pd += __shfl_xor(pd, off);
  }
  if ((lane & 15) == 0) {
    as1[wid * 4 + head] = ps;
    ad1[wid * 4 + head] = pd;
  }
}

// ---------------- layer-1 segment softmax + aggregation ----------------
// one wave per node; lane = (head, 4 channels); 2 passes over incident edges
__global__ void k_agg1(const float* __restrict__ h1, const float* __restrict__ as1,
                       const float* __restrict__ ad1, const int* __restrict__ offs,
                       const int* __restrict__ ssrc, const float* __restrict__ b1,
                       float* __restrict__ hrelu, int N) {
  int gt = blockIdx.x * blockDim.x + threadIdx.x;
  int wid = gt >> 6, lane = gt & 63;
  if (wid >= N) return;
  int head = lane >> 4, coff = (lane & 15) << 2;
  int start = offs[wid], end = offs[wid + 1];
  float ad = ad1[wid * 4 + head];
  float m = -INFINITY;
  for (int e = start; e < end; ++e) {
    int s = ssrc[e];
    float v = as1[s * 4 + head] + ad;
    v = (v > 0.f) ? v : 0.2f * v;
    m = fmaxf(m, v);
  }
  float denom = 0.f;
  float4 acc = make_float4(0.f, 0.f, 0.f, 0.f);
  for (int e = start; e < end; ++e) {
    int s = ssrc[e];
    float v = as1[s * 4 + head] + ad;
    v = (v > 0.f) ? v : 0.2f * v;
    float w = __expf(v - m);
    denom += w;
    float4 hv = *(const float4*)(h1 + (size_t)s * 256 + head * 64 + coff);
    acc.x += w * hv.x; acc.y += w * hv.y; acc.z += w * hv.z; acc.w += w * hv.w;
  }
  float inv = 1.f / denom;
  float4 bv = *(const float4*)(b1 + head * 64 + coff);
  float4 o;
  o.x = fmaxf(acc.x * inv + bv.x, 0.f);
  o.y = fmaxf(acc.y * inv + bv.y, 0.f);
  o.z = fmaxf(acc.z * inv + bv.z, 0.f);
  o.w = fmaxf(acc.w * inv + bv.w, 0.f);
  *(float4*)(hrelu + (size_t)wid * 256 + head * 64 + coff) = o;
}

// ---------------- attention logits, layer 2 (1 head x 64 ch) ----------------
__global__ void k_logits2(const float* __restrict__ h2, const float* __restrict__ a_src,
                          const float* __restrict__ a_dst, float* __restrict__ as2,
                          float* __restrict__ ad2, int N) {
  int gt = blockIdx.x * blockDim.x + threadIdx.x;
  int wid = gt >> 6, lane = gt & 63;
  if (wid >= N) return;
  float h = h2[(size_t)wid * 64 + lane];
  float ps = h * a_src[lane];
  float pd = h * a_dst[lane];
  #pragma unroll
  for (int off = 1; off < 64; off <<= 1) {
    ps += __shfl_xor(ps, off);
    pd += __shfl_xor(pd, off);
  }
  if (lane == 0) { as2[wid] = ps; ad2[wid] = pd; }
}

// ---------------- layer-2 segment softmax + aggregation ----------------
__global__ void k_agg2(const float* __restrict__ h2, const float* __restrict__ as2,
                       const float* __restrict__ ad2, const int* __restrict__ offs,
                       const int* __restrict__ ssrc, const float* __restrict__ b2,
                       float* __restrict__ hfin, int N) {
  int gt = blockIdx.x * blockDim.x + threadIdx.x;
  int wid = gt >> 6, lane = gt & 63;
  if (wid >= N) return;
  int start = offs[wid], end = offs[wid + 1];
  float ad = ad2[wid];
  float m = -INFINITY;
  for (int e = start; e < end; ++e) {
    float v = as2[ssrc[e]] + ad;
    v = (v > 0.f) ? v : 0.2f * v;
    m = fmaxf(m, v);
  }
  float denom = 0.f, acc = 0.f;
  for (int e = start; e < end; ++e) {
    int s = ssrc[e];
    float v = as2[s] + ad;
    v = (v > 0.f) ? v : 0.2f * v;
    float w = __expf(v - m);
    denom += w;
    acc += w * h2[(size_t)s * 64 + lane];
  }
  hfin[(size_t)wid * 64 + lane] = acc / denom + b2[lane];
}

// ---------------- global mean pool (batch is sorted) ----------------
__global__ void k_pool(const float* __restrict__ hfin, const int* __restrict__ gstart,
                       const int* __restrict__ gcnt, float* __restrict__ out) {
  int g = blockIdx.x;
  int c = threadIdx.x & 63, r = threadIdx.x >> 6;  // 4-way node split per graph
  int start = gstart[g], cnt = gcnt[g];
  float acc = 0.f;
  for (int i = r; i < cnt; i += 4)
    acc += hfin[(size_t)(start + i) * 64 + c];
  __shared__ float red[256];
  red[threadIdx.x] = acc;
  __syncthreads();
  if (r == 0)
    out[g * 64 + c] = (red[c] + red[64 + c] + red[128 + c] + red[192 + c]) /
                      fmaxf((float)cnt, 1.f);
}

// ---------------- launcher ----------------
extern "C" void kernel_launch(void* const* d_in, const int* in_sizes, int n_in,
                              void* d_out, int out_size, void* d_ws, size_t ws_size,
                              hipStream_t stream) {
  const float* x        = (const float*)d_in[0];
  const int*   ei       = (const int*)d_in[1];
  const int*   batch    = (const int*)d_in[2];
  const float* W1       = (const float*)d_in[3];
  const float* att_src1 = (const float*)d_in[4];
  const float* att_dst1 = (const float*)d_in[5];
  const float* b1       = (const float*)d_in[6];
  const float* W2       = (const float*)d_in[7];
  const float* att_src2 = (const float*)d_in[8];
  const float* att_dst2 = (const float*)d_in[9];
  const float* b2       = (const float*)d_in[10];
  float* out = (float*)d_out;

  const int N = in_sizes[0] / 128;   // 50000
  const int E = in_sizes[1] / 2;     // 800000
  const int EE = E + N;
  const int* esrc = ei;
  const int* edst = ei + E;

  // workspace carve (256B aligned)
  char* p = (char*)d_ws;
  auto alloc = [&](size_t bytes) -> void* {
    void* r = (void*)p;
    p += (bytes + 255) & ~(size_t)255;
    return r;
  };
  float* h1    = (float*)alloc((size_t)N * 256 * 4);
  float* hrelu = (float*)alloc((size_t)N * 256 * 4);
  float* h2    = (float*)alloc((size_t)N * 64 * 4);
  float* hfin  = (float*)alloc((size_t)N * 64 * 4);
  float* as1   = (float*)alloc((size_t)N * 4 * 4);
  float* ad1   = (float*)alloc((size_t)N * 4 * 4);
  float* as2   = (float*)alloc((size_t)N * 4);
  float* ad2   = (float*)alloc((size_t)N * 4);
  int* deg     = (int*)alloc((size_t)N * 4);
  int* offsets = (int*)alloc((size_t)(N + 1) * 4);
  int* cursor  = (int*)alloc((size_t)N * 4);
  int* ssrc    = (int*)alloc((size_t)EE * 4);
  int* gcnt    = (int*)alloc(64 * 4);
  int* gstart  = (int*)alloc(64 * 4);

  // --- build dst-sorted edge lists (counting sort, recomputed every call) ---
  k_zero_i32<<<(N + 255) / 256, 256, 0, stream>>>(deg, N);
  k_zero_i32<<<1, 64, 0, stream>>>(gcnt, 64);
  k_hist<<<1024, 256, 0, stream>>>(edst, E, N, deg);
  k_ghist<<<256, 256, 0, stream>>>(batch, N, gcnt);
  k_scan<<<1, 1024, 0, stream>>>(deg, N, offsets, cursor);
  k_gscan<<<1, 64, 0, stream>>>(gcnt, gstart);
  k_scatter<<<1024, 256, 0, stream>>>(esrc, edst, E, N, cursor, ssrc);

  // --- layer 1 ---
  k_gemm<<<dim3((N + 63) / 64, 4), 256, 0, stream>>>(x, W1, h1, N, 256, 128);
  int wave_blocks = (N * 64 + 255) / 256;
  k_logits1<<<wave_blocks, 256, 0, stream>>>(h1, att_src1, att_dst1, as1, ad1, N);
  k_agg1<<<wave_blocks, 256, 0, stream>>>(h1, as1, ad1, offsets, ssrc, b1, hrelu, N);

  // --- layer 2 ---
  k_gemm<<<dim3((N + 63) / 64, 1), 256, 0, stream>>>(hrelu, W2, h2, N, 64, 256);
  k_logits2<<<wave_blocks, 256, 0, stream>>>(h2, att_src2, att_dst2, as2, ad2, N);
  k_agg2<<<wave_blocks, 256, 0, stream>>>(h2, as2, ad2, offsets, ssrc, b2, hfin, N);

  // --- global mean pool ---
  k_pool<<<64, 256, 0, stream>>>(hfin, gstart, gcnt, out);
}

// Round 2
// 650.000 us; speedup vs baseline: 1.3934x; 1.3934x over previous
//
#include <hip/hip_runtime.h>
#include <math.h>

// ---------------- problem constants (match reference) ----------------
// N=50000, F_IN=128, HID=64, HEADS1=4 (C1=256), NUM_GRAPHS=64, slope=0.2

// ---------------- small utility kernels ----------------
__global__ void k_zero_i32(int* __restrict__ p, int n) {
  int i = blockIdx.x * blockDim.x + threadIdx.x;
  if (i < n) p[i] = 0;
}

// degree histogram over dst (real edges + implicit self loops)
__global__ void k_hist(const int* __restrict__ edst, int E, int N, int* __restrict__ deg) {
  int stride = gridDim.x * blockDim.x;
  int EE = E + N;
  for (int i = blockIdx.x * blockDim.x + threadIdx.x; i < EE; i += stride) {
    int d = (i < E) ? edst[i] : (i - E);
    atomicAdd(&deg[d], 1);
  }
}

// graph boundaries from SORTED batch array -> gstart[0..G], no atomics
__global__ void k_gbounds(const int* __restrict__ batch, int N, int G,
                          int* __restrict__ gstart) {
  int stride = gridDim.x * blockDim.x;
  for (int i = blockIdx.x * blockDim.x + threadIdx.x; i < N; i += stride) {
    int b = batch[i];
    int bp = (i == 0) ? -1 : batch[i - 1];
    for (int g = bp + 1; g <= b; ++g) gstart[g] = i;   // first node of graph g
    if (i == N - 1)
      for (int g = b + 1; g <= G; ++g) gstart[g] = N;  // trailing empties + sentinel
  }
}

// single-block exclusive scan over n entries (n ~ 50000) -> offsets[0..n], cursor copy
__global__ void k_scan(const int* __restrict__ deg, int n,
                       int* __restrict__ offsets, int* __restrict__ cursor) {
  __shared__ int buf[1024];
  __shared__ int carry_s;
  if (threadIdx.x == 0) carry_s = 0;
  __syncthreads();
  for (int base = 0; base < n; base += 1024) {
    int i = base + threadIdx.x;
    int v = (i < n) ? deg[i] : 0;
    buf[threadIdx.x] = v;
    __syncthreads();
    for (int off = 1; off < 1024; off <<= 1) {
      int t = (threadIdx.x >= off) ? buf[threadIdx.x - off] : 0;
      __syncthreads();
      buf[threadIdx.x] += t;
      __syncthreads();
    }
    int excl = buf[threadIdx.x] - v;
    int c = carry_s;
    if (i < n) { int o = c + excl; offsets[i] = o; cursor[i] = o; }
    __syncthreads();
    if (threadIdx.x == 1023) carry_s = c + buf[1023];
    __syncthreads();
  }
  if (threadIdx.x == 0) offsets[n] = carry_s;
}

// scatter edges into dst-sorted order (src ids only; self loops appended)
__global__ void k_scatter(const int* __restrict__ esrc, const int* __restrict__ edst,
                          int E, int N, int* __restrict__ cursor, int* __restrict__ ssrc) {
  int stride = gridDim.x * blockDim.x;
  int EE = E + N;
  for (int i = blockIdx.x * blockDim.x + threadIdx.x; i < EE; i += stride) {
    int d, s;
    if (i < E) { d = edst[i]; s = esrc[i]; }
    else       { d = i - E;   s = i - E;   }
    int pos = atomicAdd(&cursor[d], 1);
    ssrc[pos] = s;
  }
}

// ---------------- f32 tiled GEMM: C[M,Nn] = A[M,K] @ B[K,Nn] ----------------
// 64x64 tile, 256 threads, 4x4 micro-tile, K-step 32. K%32==0, Nn%64==0 assumed.
__global__ void k_gemm(const float* __restrict__ A, const float* __restrict__ B,
                       float* __restrict__ C, int M, int Nn, int K) {
  __shared__ float As[32][65];   // [kk][row], padded to kill write conflicts
  __shared__ float Bs[32][64];   // [kk][col]
  int tx = threadIdx.x & 15, ty = threadIdx.x >> 4;
  int row0 = blockIdx.x * 64, col0 = blockIdx.y * 64;
  float acc[4][4] = {};
  for (int k0 = 0; k0 < K; k0 += 32) {
    #pragma unroll
    for (int idx = threadIdx.x; idx < 64 * 32; idx += 256) {
      int r = idx >> 5, kk = idx & 31;
      int gr = row0 + r;
      As[kk][r] = (gr < M) ? A[(size_t)gr * K + k0 + kk] : 0.f;
    }
    #pragma unroll
    for (int idx = threadIdx.x; idx < 32 * 64; idx += 256) {
      int kk = idx >> 6, cc = idx & 63;
      Bs[kk][cc] = B[(size_t)(k0 + kk) * Nn + col0 + cc];
    }
    __syncthreads();
    #pragma unroll
    for (int kk = 0; kk < 32; ++kk) {
      float a[4], b[4];
      #pragma unroll
      for (int i = 0; i < 4; i++) a[i] = As[kk][ty * 4 + i];
      #pragma unroll
      for (int j = 0; j < 4; j++) b[j] = Bs[kk][tx * 4 + j];
      #pragma unroll
      for (int i = 0; i < 4; i++)
        #pragma unroll
        for (int j = 0; j < 4; j++)
          acc[i][j] += a[i] * b[j];
    }
    __syncthreads();
  }
  #pragma unroll
  for (int i = 0; i < 4; i++) {
    int gr = row0 + ty * 4 + i;
    if (gr < M) {
      float4 v = make_float4(acc[i][0], acc[i][1], acc[i][2], acc[i][3]);
      *(float4*)(C + (size_t)gr * Nn + col0 + tx * 4) = v;
    }
  }
}

// ---------------- attention logits, layer 1 (4 heads x 64 ch) ----------------
// one wave per node; lane covers 4 channels of one head
__global__ void k_logits1(const float* __restrict__ h1, const float* __restrict__ a_src,
                          const float* __restrict__ a_dst, float* __restrict__ as1,
                          float* __restrict__ ad1, int N) {
  int gt = blockIdx.x * blockDim.x + threadIdx.x;
  int wid = gt >> 6, lane = gt & 63;
  if (wid >= N) return;
  int head = lane >> 4, coff = (lane & 15) << 2;
  float4 hv = *(const float4*)(h1 + (size_t)wid * 256 + head * 64 + coff);
  float4 sv = *(const float4*)(a_src + head * 64 + coff);
  float4 dv = *(const float4*)(a_dst + head * 64 + coff);
  float ps = hv.x * sv.x + hv.y * sv.y + hv.z * sv.z + hv.w * sv.w;
  float pd = hv.x * dv.x + hv.y * dv.y + hv.z * dv.z + hv.w * dv.w;
  #pragma unroll
  for (int off = 1; off < 16; off <<= 1) {
    ps += __shfl_xor(ps, off);
    pd += __shfl_xor(pd, off);
  }
  if ((lane & 15) == 0) {
    as1[wid * 4 + head] = ps;
    ad1[wid * 4 + head] = pd;
  }
}

// ---------------- layer-1 segment softmax + aggregation ----------------
// one wave per node; lane = (head, 4 channels); 2 passes over incident edges
__global__ void k_agg1(const float* __restrict__ h1, const float* __restrict__ as1,
                       const float* __restrict__ ad1, const int* __restrict__ offs,
                       const int* __restrict__ ssrc, const float* __restrict__ b1,
                       float* __restrict__ hrelu, int N) {
  int gt = blockIdx.x * blockDim.x + threadIdx.x;
  int wid = gt >> 6, lane = gt & 63;
  if (wid >= N) return;
  int head = lane >> 4, coff = (lane & 15) << 2;
  int start = offs[wid], end = offs[wid + 1];
  float ad = ad1[wid * 4 + head];
  float m = -INFINITY;
  for (int e = start; e < end; ++e) {
    int s = ssrc[e];
    float v = as1[s * 4 + head] + ad;
    v = (v > 0.f) ? v : 0.2f * v;
    m = fmaxf(m, v);
  }
  float denom = 0.f;
  float4 acc = make_float4(0.f, 0.f, 0.f, 0.f);
  for (int e = start; e < end; ++e) {
    int s = ssrc[e];
    float v = as1[s * 4 + head] + ad;
    v = (v > 0.f) ? v : 0.2f * v;
    float w = __expf(v - m);
    denom += w;
    float4 hv = *(const float4*)(h1 + (size_t)s * 256 + head * 64 + coff);
    acc.x += w * hv.x; acc.y += w * hv.y; acc.z += w * hv.z; acc.w += w * hv.w;
  }
  float inv = 1.f / denom;
  float4 bv = *(const float4*)(b1 + head * 64 + coff);
  float4 o;
  o.x = fmaxf(acc.x * inv + bv.x, 0.f);
  o.y = fmaxf(acc.y * inv + bv.y, 0.f);
  o.z = fmaxf(acc.z * inv + bv.z, 0.f);
  o.w = fmaxf(acc.w * inv + bv.w, 0.f);
  *(float4*)(hrelu + (size_t)wid * 256 + head * 64 + coff) = o;
}

// ---------------- attention logits, layer 2 (1 head x 64 ch) ----------------
__global__ void k_logits2(const float* __restrict__ h2, const float* __restrict__ a_src,
                          const float* __restrict__ a_dst, float* __restrict__ as2,
                          float* __restrict__ ad2, int N) {
  int gt = blockIdx.x * blockDim.x + threadIdx.x;
  int wid = gt >> 6, lane = gt & 63;
  if (wid >= N) return;
  float h = h2[(size_t)wid * 64 + lane];
  float ps = h * a_src[lane];
  float pd = h * a_dst[lane];
  #pragma unroll
  for (int off = 1; off < 64; off <<= 1) {
    ps += __shfl_xor(ps, off);
    pd += __shfl_xor(pd, off);
  }
  if (lane == 0) { as2[wid] = ps; ad2[wid] = pd; }
}

// ---------------- layer-2 segment softmax + aggregation ----------------
__global__ void k_agg2(const float* __restrict__ h2, const float* __restrict__ as2,
                       const float* __restrict__ ad2, const int* __restrict__ offs,
                       const int* __restrict__ ssrc, const float* __restrict__ b2,
                       float* __restrict__ hfin, int N) {
  int gt = blockIdx.x * blockDim.x + threadIdx.x;
  int wid = gt >> 6, lane = gt & 63;
  if (wid >= N) return;
  int start = offs[wid], end = offs[wid + 1];
  float ad = ad2[wid];
  float m = -INFINITY;
  for (int e = start; e < end; ++e) {
    float v = as2[ssrc[e]] + ad;
    v = (v > 0.f) ? v : 0.2f * v;
    m = fmaxf(m, v);
  }
  float denom = 0.f, acc = 0.f;
  for (int e = start; e < end; ++e) {
    int s = ssrc[e];
    float v = as2[s] + ad;
    v = (v > 0.f) ? v : 0.2f * v;
    float w = __expf(v - m);
    denom += w;
    acc += w * h2[(size_t)s * 64 + lane];
  }
  hfin[(size_t)wid * 64 + lane] = acc / denom + b2[lane];
}

// ---------------- global mean pool (batch is sorted) ----------------
__global__ void k_pool(const float* __restrict__ hfin, const int* __restrict__ gstart,
                       float* __restrict__ out) {
  int g = blockIdx.x;
  int c = threadIdx.x & 63, r = threadIdx.x >> 6;  // 4-way node split per graph
  int start = gstart[g], cnt = gstart[g + 1] - start;
  float acc = 0.f;
  for (int i = r; i < cnt; i += 4)
    acc += hfin[(size_t)(start + i) * 64 + c];
  __shared__ float red[256];
  red[threadIdx.x] = acc;
  __syncthreads();
  if (r == 0)
    out[g * 64 + c] = (red[c] + red[64 + c] + red[128 + c] + red[192 + c]) /
                      fmaxf((float)cnt, 1.f);
}

// ---------------- launcher ----------------
extern "C" void kernel_launch(void* const* d_in, const int* in_sizes, int n_in,
                              void* d_out, int out_size, void* d_ws, size_t ws_size,
                              hipStream_t stream) {
  const float* x        = (const float*)d_in[0];
  const int*   ei       = (const int*)d_in[1];
  const int*   batch    = (const int*)d_in[2];
  const float* W1       = (const float*)d_in[3];
  const float* att_src1 = (const float*)d_in[4];
  const float* att_dst1 = (const float*)d_in[5];
  const float* b1       = (const float*)d_in[6];
  const float* W2       = (const float*)d_in[7];
  const float* att_src2 = (const float*)d_in[8];
  const float* att_dst2 = (const float*)d_in[9];
  const float* b2       = (const float*)d_in[10];
  float* out = (float*)d_out;

  const int N = in_sizes[0] / 128;   // 50000
  const int E = in_sizes[1] / 2;     // 800000
  const int EE = E + N;
  const int* esrc = ei;
  const int* edst = ei + E;

  // workspace carve (256B aligned)
  char* p = (char*)d_ws;
  auto alloc = [&](size_t bytes) -> void* {
    void* r = (void*)p;
    p += (bytes + 255) & ~(size_t)255;
    return r;
  };
  float* h1    = (float*)alloc((size_t)N * 256 * 4);
  float* hrelu = (float*)alloc((size_t)N * 256 * 4);
  float* h2    = (float*)alloc((size_t)N * 64 * 4);
  float* hfin  = (float*)alloc((size_t)N * 64 * 4);
  float* as1   = (float*)alloc((size_t)N * 4 * 4);
  float* ad1   = (float*)alloc((size_t)N * 4 * 4);
  float* as2   = (float*)alloc((size_t)N * 4);
  float* ad2   = (float*)alloc((size_t)N * 4);
  int* deg     = (int*)alloc((size_t)N * 4);
  int* offsets = (int*)alloc((size_t)(N + 1) * 4);
  int* cursor  = (int*)alloc((size_t)N * 4);
  int* ssrc    = (int*)alloc((size_t)EE * 4);
  int* gstart  = (int*)alloc(65 * 4);

  // --- build dst-sorted edge lists (counting sort, recomputed every call) ---
  k_zero_i32<<<(N + 255) / 256, 256, 0, stream>>>(deg, N);
  k_hist<<<1024, 256, 0, stream>>>(edst, E, N, deg);
  k_gbounds<<<256, 256, 0, stream>>>(batch, N, 64, gstart);
  k_scan<<<1, 1024, 0, stream>>>(deg, N, offsets, cursor);
  k_scatter<<<1024, 256, 0, stream>>>(esrc, edst, E, N, cursor, ssrc);

  // --- layer 1 ---
  k_gemm<<<dim3((N + 63) / 64, 4), 256, 0, stream>>>(x, W1, h1, N, 256, 128);
  int wave_blocks = (N * 64 + 255) / 256;
  k_logits1<<<wave_blocks, 256, 0, stream>>>(h1, att_src1, att_dst1, as1, ad1, N);
  k_agg1<<<wave_blocks, 256, 0, stream>>>(h1, as1, ad1, offsets, ssrc, b1, hrelu, N);

  // --- layer 2 ---
  k_gemm<<<dim3((N + 63) / 64, 1), 256, 0, stream>>>(hrelu, W2, h2, N, 64, 256);
  k_logits2<<<wave_blocks, 256, 0, stream>>>(h2, att_src2, att_dst2, as2, ad2, N);
  k_agg2<<<wave_blocks, 256, 0, stream>>>(h2, as2, ad2, offsets, ssrc, b2, hfin, N);

  // --- global mean pool ---
  k_pool<<<64, 256, 0, stream>>>(hfin, gstart, out);
}

// Round 3
// 645.391 us; speedup vs baseline: 1.4034x; 1.0071x over previous
//
#include <hip/hip_runtime.h>
#include <math.h>

// ---------------- problem constants (match reference) ----------------
// N=50000, F_IN=128, HID=64, HEADS1=4 (C1=256), NUM_GRAPHS=64, slope=0.2

typedef unsigned short ushort_t;

__device__ inline float bf2f(ushort_t u) { return __uint_as_float((unsigned)u << 16); }
__device__ inline ushort_t f2bf(float x) {            // round-to-nearest-even
  unsigned b = __float_as_uint(x);
  return (ushort_t)((b + 0x7fff + ((b >> 16) & 1)) >> 16);
}

// ---------------- small utility kernels ----------------
__global__ void k_zero_i32(int* __restrict__ p, int n) {
  int i = blockIdx.x * blockDim.x + threadIdx.x;
  if (i < n) p[i] = 0;
}

// degree histogram over dst (real edges + implicit self loops)
__global__ void k_hist(const int* __restrict__ edst, int E, int N, int* __restrict__ deg) {
  int stride = gridDim.x * blockDim.x;
  int EE = E + N;
  for (int i = blockIdx.x * blockDim.x + threadIdx.x; i < EE; i += stride) {
    int d = (i < E) ? edst[i] : (i - E);
    atomicAdd(&deg[d], 1);
  }
}

// graph boundaries from SORTED batch array -> gstart[0..G], no atomics
__global__ void k_gbounds(const int* __restrict__ batch, int N, int G,
                          int* __restrict__ gstart) {
  int stride = gridDim.x * blockDim.x;
  for (int i = blockIdx.x * blockDim.x + threadIdx.x; i < N; i += stride) {
    int b = batch[i];
    int bp = (i == 0) ? -1 : batch[i - 1];
    for (int g = bp + 1; g <= b; ++g) gstart[g] = i;   // first node of graph g
    if (i == N - 1)
      for (int g = b + 1; g <= G; ++g) gstart[g] = N;  // trailing empties + sentinel
  }
}

// single-block exclusive scan over n entries (n ~ 50000) -> offsets[0..n], cursor copy
__global__ void k_scan(const int* __restrict__ deg, int n,
                       int* __restrict__ offsets, int* __restrict__ cursor) {
  __shared__ int buf[1024];
  __shared__ int carry_s;
  if (threadIdx.x == 0) carry_s = 0;
  __syncthreads();
  for (int base = 0; base < n; base += 1024) {
    int i = base + threadIdx.x;
    int v = (i < n) ? deg[i] : 0;
    buf[threadIdx.x] = v;
    __syncthreads();
    for (int off = 1; off < 1024; off <<= 1) {
      int t = (threadIdx.x >= off) ? buf[threadIdx.x - off] : 0;
      __syncthreads();
      buf[threadIdx.x] += t;
      __syncthreads();
    }
    int excl = buf[threadIdx.x] - v;
    int c = carry_s;
    if (i < n) { int o = c + excl; offsets[i] = o; cursor[i] = o; }
    __syncthreads();
    if (threadIdx.x == 1023) carry_s = c + buf[1023];
    __syncthreads();
  }
  if (threadIdx.x == 0) offsets[n] = carry_s;
}

// scatter edges into dst-sorted order (src ids only; self loops appended)
__global__ void k_scatter(const int* __restrict__ esrc, const int* __restrict__ edst,
                          int E, int N, int* __restrict__ cursor, int* __restrict__ ssrc) {
  int stride = gridDim.x * blockDim.x;
  int EE = E + N;
  for (int i = blockIdx.x * blockDim.x + threadIdx.x; i < EE; i += stride) {
    int d, s;
    if (i < E) { d = edst[i]; s = esrc[i]; }
    else       { d = i - E;   s = i - E;   }
    int pos = atomicAdd(&cursor[d], 1);
    ssrc[pos] = s;
  }
}

// ---------------- f32 tiled GEMM: C[M,Nn] = A[M,K] @ B[K,Nn] ----------------
// 64x64 tile, 256 threads, 4x4 micro-tile, K-step 32. K%32==0, Nn%64==0 assumed.
__global__ void k_gemm(const float* __restrict__ A, const float* __restrict__ B,
                       float* __restrict__ C, int M, int Nn, int K) {
  __shared__ float As[32][65];   // [kk][row], padded to kill write conflicts
  __shared__ float Bs[32][64];   // [kk][col]
  int tx = threadIdx.x & 15, ty = threadIdx.x >> 4;
  int row0 = blockIdx.x * 64, col0 = blockIdx.y * 64;
  float acc[4][4] = {};
  for (int k0 = 0; k0 < K; k0 += 32) {
    #pragma unroll
    for (int idx = threadIdx.x; idx < 64 * 32; idx += 256) {
      int r = idx >> 5, kk = idx & 31;
      int gr = row0 + r;
      As[kk][r] = (gr < M) ? A[(size_t)gr * K + k0 + kk] : 0.f;
    }
    #pragma unroll
    for (int idx = threadIdx.x; idx < 32 * 64; idx += 256) {
      int kk = idx >> 6, cc = idx & 63;
      Bs[kk][cc] = B[(size_t)(k0 + kk) * Nn + col0 + cc];
    }
    __syncthreads();
    #pragma unroll
    for (int kk = 0; kk < 32; ++kk) {
      float a[4], b[4];
      #pragma unroll
      for (int i = 0; i < 4; i++) a[i] = As[kk][ty * 4 + i];
      #pragma unroll
      for (int j = 0; j < 4; j++) b[j] = Bs[kk][tx * 4 + j];
      #pragma unroll
      for (int i = 0; i < 4; i++)
        #pragma unroll
        for (int j = 0; j < 4; j++)
          acc[i][j] += a[i] * b[j];
    }
    __syncthreads();
  }
  #pragma unroll
  for (int i = 0; i < 4; i++) {
    int gr = row0 + ty * 4 + i;
    if (gr < M) {
      float4 v = make_float4(acc[i][0], acc[i][1], acc[i][2], acc[i][3]);
      *(float4*)(C + (size_t)gr * Nn + col0 + tx * 4) = v;
    }
  }
}

// ---------------- attention logits, layer 1 + bf16 copy of h1 ----------------
// one wave per node; lane covers 4 channels of one head
__global__ void k_logits1(const float* __restrict__ h1, const float* __restrict__ a_src,
                          const float* __restrict__ a_dst, float* __restrict__ as1,
                          float* __restrict__ ad1, ushort_t* __restrict__ h1b, int N) {
  int gt = blockIdx.x * blockDim.x + threadIdx.x;
  int wid = gt >> 6, lane = gt & 63;
  if (wid >= N) return;
  int head = lane >> 4, coff = (lane & 15) << 2;
  float4 hv = *(const float4*)(h1 + (size_t)wid * 256 + head * 64 + coff);
  // bf16 copy for the gather in k_agg1
  ushort4 hb;
  hb.x = f2bf(hv.x); hb.y = f2bf(hv.y); hb.z = f2bf(hv.z); hb.w = f2bf(hv.w);
  *(ushort4*)(h1b + (size_t)wid * 256 + head * 64 + coff) = hb;
  float4 sv = *(const float4*)(a_src + head * 64 + coff);
  float4 dv = *(const float4*)(a_dst + head * 64 + coff);
  float ps = hv.x * sv.x + hv.y * sv.y + hv.z * sv.z + hv.w * sv.w;
  float pd = hv.x * dv.x + hv.y * dv.y + hv.z * dv.z + hv.w * dv.w;
  #pragma unroll
  for (int off = 1; off < 16; off <<= 1) {
    ps += __shfl_xor(ps, off);
    pd += __shfl_xor(pd, off);
  }
  if ((lane & 15) == 0) {
    as1[wid * 4 + head] = ps;
    ad1[wid * 4 + head] = pd;
  }
}

// ---------------- layer-1 segment softmax + aggregation (bf16 gather) ----------------
__global__ void k_agg1(const ushort_t* __restrict__ h1b, const float* __restrict__ as1,
                       const float* __restrict__ ad1, const int* __restrict__ offs,
                       const int* __restrict__ ssrc, const float* __restrict__ b1,
                       float* __restrict__ hrelu, int N) {
  int gt = blockIdx.x * blockDim.x + threadIdx.x;
  int wid = gt >> 6, lane = gt & 63;
  if (wid >= N) return;
  int head = lane >> 4, coff = (lane & 15) << 2;
  int start = offs[wid], end = offs[wid + 1];
  float ad = ad1[wid * 4 + head];
  float m = -INFINITY;
  for (int e = start; e < end; ++e) {
    int s = ssrc[e];
    float v = as1[s * 4 + head] + ad;
    v = (v > 0.f) ? v : 0.2f * v;
    m = fmaxf(m, v);
  }
  float denom = 0.f;
  float4 acc = make_float4(0.f, 0.f, 0.f, 0.f);
  for (int e = start; e < end; ++e) {
    int s = ssrc[e];
    float v = as1[s * 4 + head] + ad;
    v = (v > 0.f) ? v : 0.2f * v;
    float w = __expf(v - m);
    denom += w;
    ushort4 hv = *(const ushort4*)(h1b + (size_t)s * 256 + head * 64 + coff);
    acc.x += w * bf2f(hv.x); acc.y += w * bf2f(hv.y);
    acc.z += w * bf2f(hv.z); acc.w += w * bf2f(hv.w);
  }
  float inv = 1.f / denom;
  float4 bv = *(const float4*)(b1 + head * 64 + coff);
  float4 o;
  o.x = fmaxf(acc.x * inv + bv.x, 0.f);
  o.y = fmaxf(acc.y * inv + bv.y, 0.f);
  o.z = fmaxf(acc.z * inv + bv.z, 0.f);
  o.w = fmaxf(acc.w * inv + bv.w, 0.f);
  *(float4*)(hrelu + (size_t)wid * 256 + head * 64 + coff) = o;
}

// ---------------- attention logits, layer 2 + bf16 copy of h2 ----------------
__global__ void k_logits2(const float* __restrict__ h2, const float* __restrict__ a_src,
                          const float* __restrict__ a_dst, float* __restrict__ as2,
                          float* __restrict__ ad2, ushort_t* __restrict__ h2b, int N) {
  int gt = blockIdx.x * blockDim.x + threadIdx.x;
  int wid = gt >> 6, lane = gt & 63;
  if (wid >= N) return;
  float h = h2[(size_t)wid * 64 + lane];
  h2b[(size_t)wid * 64 + lane] = f2bf(h);
  float ps = h * a_src[lane];
  float pd = h * a_dst[lane];
  #pragma unroll
  for (int off = 1; off < 64; off <<= 1) {
    ps += __shfl_xor(ps, off);
    pd += __shfl_xor(pd, off);
  }
  if (lane == 0) { as2[wid] = ps; ad2[wid] = pd; }
}

// ---------------- layer-2 segment softmax + aggregation (bf16 gather) ----------------
__global__ void k_agg2(const ushort_t* __restrict__ h2b, const float* __restrict__ as2,
                       const float* __restrict__ ad2, const int* __restrict__ offs,
                       const int* __restrict__ ssrc, const float* __restrict__ b2,
                       float* __restrict__ hfin, int N) {
  int gt = blockIdx.x * blockDim.x + threadIdx.x;
  int wid = gt >> 6, lane = gt & 63;
  if (wid >= N) return;
  int start = offs[wid], end = offs[wid + 1];
  float ad = ad2[wid];
  float m = -INFINITY;
  for (int e = start; e < end; ++e) {
    float v = as2[ssrc[e]] + ad;
    v = (v > 0.f) ? v : 0.2f * v;
    m = fmaxf(m, v);
  }
  float denom = 0.f, acc = 0.f;
  for (int e = start; e < end; ++e) {
    int s = ssrc[e];
    float v = as2[s] + ad;
    v = (v > 0.f) ? v : 0.2f * v;
    float w = __expf(v - m);
    denom += w;
    acc += w * bf2f(h2b[(size_t)s * 64 + lane]);
  }
  hfin[(size_t)wid * 64 + lane] = acc / denom + b2[lane];
}

// ---------------- global mean pool (batch is sorted) ----------------
__global__ void k_pool(const float* __restrict__ hfin, const int* __restrict__ gstart,
                       float* __restrict__ out) {
  int g = blockIdx.x;
  int c = threadIdx.x & 63, r = threadIdx.x >> 6;  // 4-way node split per graph
  int start = gstart[g], cnt = gstart[g + 1] - start;
  float acc = 0.f;
  for (int i = r; i < cnt; i += 4)
    acc += hfin[(size_t)(start + i) * 64 + c];
  __shared__ float red[256];
  red[threadIdx.x] = acc;
  __syncthreads();
  if (r == 0)
    out[g * 64 + c] = (red[c] + red[64 + c] + red[128 + c] + red[192 + c]) /
                      fmaxf((float)cnt, 1.f);
}

// ---------------- launcher ----------------
extern "C" void kernel_launch(void* const* d_in, const int* in_sizes, int n_in,
                              void* d_out, int out_size, void* d_ws, size_t ws_size,
                              hipStream_t stream) {
  const float* x        = (const float*)d_in[0];
  const int*   ei       = (const int*)d_in[1];
  const int*   batch    = (const int*)d_in[2];
  const float* W1       = (const float*)d_in[3];
  const float* att_src1 = (const float*)d_in[4];
  const float* att_dst1 = (const float*)d_in[5];
  const float* b1       = (const float*)d_in[6];
  const float* W2       = (const float*)d_in[7];
  const float* att_src2 = (const float*)d_in[8];
  const float* att_dst2 = (const float*)d_in[9];
  const float* b2       = (const float*)d_in[10];
  float* out = (float*)d_out;

  const int N = in_sizes[0] / 128;   // 50000
  const int E = in_sizes[1] / 2;     // 800000
  const int EE = E + N;
  const int* esrc = ei;
  const int* edst = ei + E;

  // workspace carve (256B aligned)
  char* p = (char*)d_ws;
  auto alloc = [&](size_t bytes) -> void* {
    void* r = (void*)p;
    p += (bytes + 255) & ~(size_t)255;
    return r;
  };
  float*    h1    = (float*)alloc((size_t)N * 256 * 4);     // also reused as hrelu
  ushort_t* h1b   = (ushort_t*)alloc((size_t)N * 256 * 2);
  float*    h2    = (float*)alloc((size_t)N * 64 * 4);      // also reused as hfin
  ushort_t* h2b   = (ushort_t*)alloc((size_t)N * 64 * 2);
  float*    as1   = (float*)alloc((size_t)N * 4 * 4);
  float*    ad1   = (float*)alloc((size_t)N * 4 * 4);
  float*    as2   = (float*)alloc((size_t)N * 4);
  float*    ad2   = (float*)alloc((size_t)N * 4);
  int* deg     = (int*)alloc((size_t)N * 4);
  int* offsets = (int*)alloc((size_t)(N + 1) * 4);
  int* cursor  = (int*)alloc((size_t)N * 4);
  int* ssrc    = (int*)alloc((size_t)EE * 4);
  int* gstart  = (int*)alloc(65 * 4);
  float* hrelu = h1;   // safe alias: k_agg1 reads only h1b/as1/ad1
  float* hfin  = h2;   // safe alias: k_agg2 reads only h2b/as2/ad2

  // --- build dst-sorted edge lists (counting sort, recomputed every call) ---
  k_zero_i32<<<(N + 255) / 256, 256, 0, stream>>>(deg, N);
  k_hist<<<1024, 256, 0, stream>>>(edst, E, N, deg);
  k_gbounds<<<256, 256, 0, stream>>>(batch, N, 64, gstart);
  k_scan<<<1, 1024, 0, stream>>>(deg, N, offsets, cursor);
  k_scatter<<<1024, 256, 0, stream>>>(esrc, edst, E, N, cursor, ssrc);

  // --- layer 1 ---
  k_gemm<<<dim3((N + 63) / 64, 4), 256, 0, stream>>>(x, W1, h1, N, 256, 128);
  int wave_blocks = (N * 64 + 255) / 256;
  k_logits1<<<wave_blocks, 256, 0, stream>>>(h1, att_src1, att_dst1, as1, ad1, h1b, N);
  k_agg1<<<wave_blocks, 256, 0, stream>>>(h1b, as1, ad1, offsets, ssrc, b1, hrelu, N);

  // --- layer 2 ---
  k_gemm<<<dim3((N + 63) / 64, 1), 256, 0, stream>>>(hrelu, W2, h2, N, 64, 256);
  k_logits2<<<wave_blocks, 256, 0, stream>>>(h2, att_src2, att_dst2, as2, ad2, h2b, N);
  k_agg2<<<wave_blocks, 256, 0, stream>>>(h2b, as2, ad2, offsets, ssrc, b2, hfin, N);

  // --- global mean pool ---
  k_pool<<<64, 256, 0, stream>>>(hfin, gstart, out);
}

// Round 4
// 457.391 us; speedup vs baseline: 1.9802x; 1.4110x over previous
//
#include <hip/hip_runtime.h>
#include <math.h>

// ---------------- problem constants (match reference) ----------------
// N=50000, F_IN=128, HID=64, HEADS1=4 (C1=256), NUM_GRAPHS=64, slope=0.2

typedef unsigned short ushort_t;

__device__ inline float bf2f(ushort_t u) { return __uint_as_float((unsigned)u << 16); }
__device__ inline ushort_t f2bf(float x) {            // round-to-nearest-even
  unsigned b = __float_as_uint(x);
  return (ushort_t)((b + 0x7fff + ((b >> 16) & 1)) >> 16);
}
__device__ inline float leaky(float v) { return (v > 0.f) ? v : 0.2f * v; }

// ---------------- small utility kernels ----------------
__global__ void k_zero_i32(int* __restrict__ p, int n) {
  int i = blockIdx.x * blockDim.x + threadIdx.x;
  if (i < n) p[i] = 0;
}

// degree histogram over dst (real edges + implicit self loops)
__global__ void k_hist(const int* __restrict__ edst, int E, int N, int* __restrict__ deg) {
  int stride = gridDim.x * blockDim.x;
  int EE = E + N;
  for (int i = blockIdx.x * blockDim.x + threadIdx.x; i < EE; i += stride) {
    int d = (i < E) ? edst[i] : (i - E);
    atomicAdd(&deg[d], 1);
  }
}

// graph boundaries from SORTED batch array -> gstart[0..G], no atomics
__global__ void k_gbounds(const int* __restrict__ batch, int N, int G,
                          int* __restrict__ gstart) {
  int stride = gridDim.x * blockDim.x;
  for (int i = blockIdx.x * blockDim.x + threadIdx.x; i < N; i += stride) {
    int b = batch[i];
    int bp = (i == 0) ? -1 : batch[i - 1];
    for (int g = bp + 1; g <= b; ++g) gstart[g] = i;   // first node of graph g
    if (i == N - 1)
      for (int g = b + 1; g <= G; ++g) gstart[g] = N;  // trailing empties + sentinel
  }
}

// single-block exclusive scan; wave-shfl scan + cross-wave LDS, 2 barriers/chunk
__global__ void k_scan(const int* __restrict__ deg, int n,
                       int* __restrict__ offsets, int* __restrict__ cursor) {
  __shared__ int wsum[16];
  __shared__ int carry_s;
  int tid = threadIdx.x, lane = tid & 63, wv = tid >> 6;
  if (tid == 0) carry_s = 0;
  __syncthreads();
  for (int base = 0; base < n; base += 1024) {
    int i = base + tid;
    int v = (i < n) ? deg[i] : 0;
    int x = v;                                  // inclusive intra-wave scan
    #pragma unroll
    for (int off = 1; off < 64; off <<= 1) {
      int t = __shfl_up(x, off);
      if (lane >= off) x += t;
    }
    if (lane == 63) wsum[wv] = x;
    __syncthreads();
    if (wv == 0 && lane < 16) {                 // scan the 16 wave totals
      int s = wsum[lane];
      #pragma unroll
      for (int off = 1; off < 16; off <<= 1) {
        int t = __shfl_up(s, off);
        if (lane >= off) s += t;
      }
      wsum[lane] = s;                           // inclusive
    }
    __syncthreads();
    int wbase = (wv == 0) ? 0 : wsum[wv - 1];
    int incl = carry_s + wbase + x;
    if (i < n) { int o = incl - v; offsets[i] = o; cursor[i] = o; }
    __syncthreads();                            // everyone read carry_s
    if (tid == 1023) carry_s = incl;            // chunk total
    __syncthreads();
  }
  if (tid == 0) offsets[n] = carry_s;
}

// scatter edges into dst-sorted order (src ids only; self loops appended)
__global__ void k_scatter(const int* __restrict__ esrc, const int* __restrict__ edst,
                          int E, int N, int* __restrict__ cursor, int* __restrict__ ssrc) {
  int stride = gridDim.x * blockDim.x;
  int EE = E + N;
  for (int i = blockIdx.x * blockDim.x + threadIdx.x; i < EE; i += stride) {
    int d, s;
    if (i < E) { d = edst[i]; s = esrc[i]; }
    else       { d = i - E;   s = i - E;   }
    int pos = atomicAdd(&cursor[d], 1);
    ssrc[pos] = s;
  }
}

// ---------------- f32 tiled GEMM: C[M,Nn] = A[M,K] @ B[K,Nn] ----------------
__global__ void k_gemm(const float* __restrict__ A, const float* __restrict__ B,
                       float* __restrict__ C, int M, int Nn, int K) {
  __shared__ float As[32][65];   // [kk][row], padded
  __shared__ float Bs[32][64];   // [kk][col]
  int tx = threadIdx.x & 15, ty = threadIdx.x >> 4;
  int row0 = blockIdx.x * 64, col0 = blockIdx.y * 64;
  float acc[4][4] = {};
  for (int k0 = 0; k0 < K; k0 += 32) {
    #pragma unroll
    for (int idx = threadIdx.x; idx < 64 * 32; idx += 256) {
      int r = idx >> 5, kk = idx & 31;
      int gr = row0 + r;
      As[kk][r] = (gr < M) ? A[(size_t)gr * K + k0 + kk] : 0.f;
    }
    #pragma unroll
    for (int idx = threadIdx.x; idx < 32 * 64; idx += 256) {
      int kk = idx >> 6, cc = idx & 63;
      Bs[kk][cc] = B[(size_t)(k0 + kk) * Nn + col0 + cc];
    }
    __syncthreads();
    #pragma unroll
    for (int kk = 0; kk < 32; ++kk) {
      float a[4], b[4];
      #pragma unroll
      for (int i = 0; i < 4; i++) a[i] = As[kk][ty * 4 + i];
      #pragma unroll
      for (int j = 0; j < 4; j++) b[j] = Bs[kk][tx * 4 + j];
      #pragma unroll
      for (int i = 0; i < 4; i++)
        #pragma unroll
        for (int j = 0; j < 4; j++)
          acc[i][j] += a[i] * b[j];
    }
    __syncthreads();
  }
  #pragma unroll
  for (int i = 0; i < 4; i++) {
    int gr = row0 + ty * 4 + i;
    if (gr < M) {
      float4 v = make_float4(acc[i][0], acc[i][1], acc[i][2], acc[i][3]);
      *(float4*)(C + (size_t)gr * Nn + col0 + tx * 4) = v;
    }
  }
}

// ---------------- attention logits, layer 1 + bf16 copy of h1 ----------------
__global__ void k_logits1(const float* __restrict__ h1, const float* __restrict__ a_src,
                          const float* __restrict__ a_dst, float* __restrict__ as1,
                          float* __restrict__ ad1, ushort_t* __restrict__ h1b, int N) {
  int gt = blockIdx.x * blockDim.x + threadIdx.x;
  int wid = gt >> 6, lane = gt & 63;
  if (wid >= N) return;
  int head = lane >> 4, coff = (lane & 15) << 2;
  float4 hv = *(const float4*)(h1 + (size_t)wid * 256 + head * 64 + coff);
  ushort4 hb;
  hb.x = f2bf(hv.x); hb.y = f2bf(hv.y); hb.z = f2bf(hv.z); hb.w = f2bf(hv.w);
  *(ushort4*)(h1b + (size_t)wid * 256 + head * 64 + coff) = hb;
  float4 sv = *(const float4*)(a_src + head * 64 + coff);
  float4 dv = *(const float4*)(a_dst + head * 64 + coff);
  float ps = hv.x * sv.x + hv.y * sv.y + hv.z * sv.z + hv.w * sv.w;
  float pd = hv.x * dv.x + hv.y * dv.y + hv.z * dv.z + hv.w * dv.w;
  #pragma unroll
  for (int off = 1; off < 16; off <<= 1) {
    ps += __shfl_xor(ps, off);
    pd += __shfl_xor(pd, off);
  }
  if ((lane & 15) == 0) {
    as1[wid * 4 + head] = ps;
    ad1[wid * 4 + head] = pd;
  }
}

// ---------------- layer-1 segment softmax + aggregation ----------------
// pass 1: edge-parallel max across 16 lanes/head; pass 2: unroll-4 gather
__global__ void k_agg1(const ushort_t* __restrict__ h1b, const float* __restrict__ as1,
                       const float* __restrict__ ad1, const int* __restrict__ offs,
                       const int* __restrict__ ssrc, const float* __restrict__ b1,
                       float* __restrict__ hrelu, int N) {
  int gt = blockIdx.x * blockDim.x + threadIdx.x;
  int wid = gt >> 6, lane = gt & 63;
  if (wid >= N) return;
  int head = lane >> 4, sub = lane & 15, coff = sub << 2;
  int start = offs[wid], end = offs[wid + 1];
  float ad = ad1[wid * 4 + head];

  // pass 1: max, edge-parallel within head group
  float m = -INFINITY;
  for (int e = start + sub; e < end; e += 16) {
    int s = ssrc[e];
    m = fmaxf(m, leaky(as1[s * 4 + head] + ad));
  }
  #pragma unroll
  for (int off = 1; off < 16; off <<= 1) m = fmaxf(m, __shfl_xor(m, off));

  // pass 2: exp-weighted gather, 4 edges in flight
  float denom = 0.f;
  float4 acc = make_float4(0.f, 0.f, 0.f, 0.f);
  int e = start;
  for (; e + 4 <= end; e += 4) {
    int s0 = ssrc[e], s1 = ssrc[e + 1], s2 = ssrc[e + 2], s3 = ssrc[e + 3];
    ushort4 g0 = *(const ushort4*)(h1b + (size_t)s0 * 256 + head * 64 + coff);
    ushort4 g1 = *(const ushort4*)(h1b + (size_t)s1 * 256 + head * 64 + coff);
    ushort4 g2 = *(const ushort4*)(h1b + (size_t)s2 * 256 + head * 64 + coff);
    ushort4 g3 = *(const ushort4*)(h1b + (size_t)s3 * 256 + head * 64 + coff);
    float w0 = __expf(leaky(as1[s0 * 4 + head] + ad) - m);
    float w1 = __expf(leaky(as1[s1 * 4 + head] + ad) - m);
    float w2 = __expf(leaky(as1[s2 * 4 + head] + ad) - m);
    float w3 = __expf(leaky(as1[s3 * 4 + head] + ad) - m);
    denom += (w0 + w1) + (w2 + w3);
    acc.x += w0 * bf2f(g0.x) + w1 * bf2f(g1.x) + w2 * bf2f(g2.x) + w3 * bf2f(g3.x);
    acc.y += w0 * bf2f(g0.y) + w1 * bf2f(g1.y) + w2 * bf2f(g2.y) + w3 * bf2f(g3.y);
    acc.z += w0 * bf2f(g0.z) + w1 * bf2f(g1.z) + w2 * bf2f(g2.z) + w3 * bf2f(g3.z);
    acc.w += w0 * bf2f(g0.w) + w1 * bf2f(g1.w) + w2 * bf2f(g2.w) + w3 * bf2f(g3.w);
  }
  for (; e < end; ++e) {
    int s = ssrc[e];
    float w = __expf(leaky(as1[s * 4 + head] + ad) - m);
    ushort4 g = *(const ushort4*)(h1b + (size_t)s * 256 + head * 64 + coff);
    denom += w;
    acc.x += w * bf2f(g.x); acc.y += w * bf2f(g.y);
    acc.z += w * bf2f(g.z); acc.w += w * bf2f(g.w);
  }
  float inv = 1.f / denom;
  float4 bv = *(const float4*)(b1 + head * 64 + coff);
  float4 o;
  o.x = fmaxf(acc.x * inv + bv.x, 0.f);
  o.y = fmaxf(acc.y * inv + bv.y, 0.f);
  o.z = fmaxf(acc.z * inv + bv.z, 0.f);
  o.w = fmaxf(acc.w * inv + bv.w, 0.f);
  *(float4*)(hrelu + (size_t)wid * 256 + head * 64 + coff) = o;
}

// ---------------- attention logits, layer 2 + bf16 copy of h2 ----------------
__global__ void k_logits2(const float* __restrict__ h2, const float* __restrict__ a_src,
                          const float* __restrict__ a_dst, float* __restrict__ as2,
                          float* __restrict__ ad2, ushort_t* __restrict__ h2b, int N) {
  int gt = blockIdx.x * blockDim.x + threadIdx.x;
  int wid = gt >> 6, lane = gt & 63;
  if (wid >= N) return;
  float h = h2[(size_t)wid * 64 + lane];
  h2b[(size_t)wid * 64 + lane] = f2bf(h);
  float ps = h * a_src[lane];
  float pd = h * a_dst[lane];
  #pragma unroll
  for (int off = 1; off < 64; off <<= 1) {
    ps += __shfl_xor(ps, off);
    pd += __shfl_xor(pd, off);
  }
  if (lane == 0) { as2[wid] = ps; ad2[wid] = pd; }
}

// ---------------- layer-2 segment softmax + aggregation ----------------
__global__ void k_agg2(const ushort_t* __restrict__ h2b, const float* __restrict__ as2,
                       const float* __restrict__ ad2, const int* __restrict__ offs,
                       const int* __restrict__ ssrc, const float* __restrict__ b2,
                       float* __restrict__ hfin, int N) {
  int gt = blockIdx.x * blockDim.x + threadIdx.x;
  int wid = gt >> 6, lane = gt & 63;
  if (wid >= N) return;
  int start = offs[wid], end = offs[wid + 1];
  float ad = ad2[wid];

  // pass 1: max, edge-parallel across all 64 lanes
  float m = -INFINITY;
  for (int e = start + lane; e < end; e += 64) {
    m = fmaxf(m, leaky(as2[ssrc[e]] + ad));
  }
  #pragma unroll
  for (int off = 1; off < 64; off <<= 1) m = fmaxf(m, __shfl_xor(m, off));

  // pass 2: unroll-4
  float denom = 0.f, acc = 0.f;
  int e = start;
  for (; e + 4 <= end; e += 4) {
    int s0 = ssrc[e], s1 = ssrc[e + 1], s2 = ssrc[e + 2], s3 = ssrc[e + 3];
    float g0 = bf2f(h2b[(size_t)s0 * 64 + lane]);
    float g1 = bf2f(h2b[(size_t)s1 * 64 + lane]);
    float g2 = bf2f(h2b[(size_t)s2 * 64 + lane]);
    float g3 = bf2f(h2b[(size_t)s3 * 64 + lane]);
    float w0 = __expf(leaky(as2[s0] + ad) - m);
    float w1 = __expf(leaky(as2[s1] + ad) - m);
    float w2 = __expf(leaky(as2[s2] + ad) - m);
    float w3 = __expf(leaky(as2[s3] + ad) - m);
    denom += (w0 + w1) + (w2 + w3);
    acc += w0 * g0 + w1 * g1 + w2 * g2 + w3 * g3;
  }
  for (; e < end; ++e) {
    int s = ssrc[e];
    float w = __expf(leaky(as2[s] + ad) - m);
    denom += w;
    acc += w * bf2f(h2b[(size_t)s * 64 + lane]);
  }
  hfin[(size_t)wid * 64 + lane] = acc / denom + b2[lane];
}

// ---------------- global mean pool (batch is sorted) ----------------
__global__ void k_pool(const float* __restrict__ hfin, const int* __restrict__ gstart,
                       float* __restrict__ out) {
  int g = blockIdx.x;
  int c = threadIdx.x & 63, r = threadIdx.x >> 6;
  int start = gstart[g], cnt = gstart[g + 1] - start;
  float acc = 0.f;
  for (int i = r; i < cnt; i += 4)
    acc += hfin[(size_t)(start + i) * 64 + c];
  __shared__ float red[256];
  red[threadIdx.x] = acc;
  __syncthreads();
  if (r == 0)
    out[g * 64 + c] = (red[c] + red[64 + c] + red[128 + c] + red[192 + c]) /
                      fmaxf((float)cnt, 1.f);
}

// ---------------- launcher ----------------
extern "C" void kernel_launch(void* const* d_in, const int* in_sizes, int n_in,
                              void* d_out, int out_size, void* d_ws, size_t ws_size,
                              hipStream_t stream) {
  const float* x        = (const float*)d_in[0];
  const int*   ei       = (const int*)d_in[1];
  const int*   batch    = (const int*)d_in[2];
  const float* W1       = (const float*)d_in[3];
  const float* att_src1 = (const float*)d_in[4];
  const float* att_dst1 = (const float*)d_in[5];
  const float* b1       = (const float*)d_in[6];
  const float* W2       = (const float*)d_in[7];
  const float* att_src2 = (const float*)d_in[8];
  const float* att_dst2 = (const float*)d_in[9];
  const float* b2       = (const float*)d_in[10];
  float* out = (float*)d_out;

  const int N = in_sizes[0] / 128;   // 50000
  const int E = in_sizes[1] / 2;     // 800000
  const int EE = E + N;
  const int* esrc = ei;
  const int* edst = ei + E;

  // workspace carve (256B aligned)
  char* p = (char*)d_ws;
  auto alloc = [&](size_t bytes) -> void* {
    void* r = (void*)p;
    p += (bytes + 255) & ~(size_t)255;
    return r;
  };
  float*    h1    = (float*)alloc((size_t)N * 256 * 4);     // also reused as hrelu
  ushort_t* h1b   = (ushort_t*)alloc((size_t)N * 256 * 2);
  float*    h2    = (float*)alloc((size_t)N * 64 * 4);      // also reused as hfin
  ushort_t* h2b   = (ushort_t*)alloc((size_t)N * 64 * 2);
  float*    as1   = (float*)alloc((size_t)N * 4 * 4);
  float*    ad1   = (float*)alloc((size_t)N * 4 * 4);
  float*    as2   = (float*)alloc((size_t)N * 4);
  float*    ad2   = (float*)alloc((size_t)N * 4);
  int* deg     = (int*)alloc((size_t)N * 4);
  int* offsets = (int*)alloc((size_t)(N + 1) * 4);
  int* cursor  = (int*)alloc((size_t)N * 4);
  int* ssrc    = (int*)alloc((size_t)EE * 4);
  int* gstart  = (int*)alloc(65 * 4);
  float* hrelu = h1;   // safe alias: k_agg1 reads only h1b/as1/ad1
  float* hfin  = h2;   // safe alias: k_agg2 reads only h2b/as2/ad2

  // --- build dst-sorted edge lists (counting sort, recomputed every call) ---
  k_zero_i32<<<(N + 255) / 256, 256, 0, stream>>>(deg, N);
  k_hist<<<1024, 256, 0, stream>>>(edst, E, N, deg);
  k_gbounds<<<256, 256, 0, stream>>>(batch, N, 64, gstart);
  k_scan<<<1, 1024, 0, stream>>>(deg, N, offsets, cursor);
  k_scatter<<<1024, 256, 0, stream>>>(esrc, edst, E, N, cursor, ssrc);

  // --- layer 1 ---
  k_gemm<<<dim3((N + 63) / 64, 4), 256, 0, stream>>>(x, W1, h1, N, 256, 128);
  int wave_blocks = (N * 64 + 255) / 256;
  k_logits1<<<wave_blocks, 256, 0, stream>>>(h1, att_src1, att_dst1, as1, ad1, h1b, N);
  k_agg1<<<wave_blocks, 256, 0, stream>>>(h1b, as1, ad1, offsets, ssrc, b1, hrelu, N);

  // --- layer 2 ---
  k_gemm<<<dim3((N + 63) / 64, 1), 256, 0, stream>>>(hrelu, W2, h2, N, 64, 256);
  k_logits2<<<wave_blocks, 256, 0, stream>>>(h2, att_src2, att_dst2, as2, ad2, h2b, N);
  k_agg2<<<wave_blocks, 256, 0, stream>>>(h2b, as2, ad2, offsets, ssrc, b2, hfin, N);

  // --- global mean pool ---
  k_pool<<<64, 256, 0, stream>>>(hfin, gstart, out);
}